// Round 9
// baseline (55.080 us; speedup 1.0000x reference)
//
#include <hip/hip_runtime.h>
#include <hip/hip_cooperative_groups.h>

namespace cg = cooperative_groups;

// DSSIM loss: y_pred, y_true [8,3,512,512] fp32 -> scalar mean DSSIM.
// R9: single cooperative dispatch (grid=256 = 1 block/CU co-resident).
//  - R8 tiling: thread = 4 cols x 4 rows, each input row loaded once,
//    vertical rowsum exchange via LDS (now ONE merged publish phase, 80KB),
//    horizontal halo via post-hoc shfl + edge LDS patch.
//  - partials to d_ws, grid.sync(), block 0 reduces in-kernel (no 2nd node).

#define N_IMG 8
#define C_CH 3
#define H_DIM 512
#define W_DIM 512
#define BLOCK 512
#define GRID 256   // 8 img x 32 bands of 16 rows; exactly 1 block per CU

__global__ __launch_bounds__(BLOCK, 2) void dssim_coop(
        const float* __restrict__ yp,
        const float* __restrict__ yt,
        float* __restrict__ ws,
        float* __restrict__ out) {
    const int tid   = threadIdx.x;
    const int lane  = tid & 63;
    const int wv    = tid >> 6;         // 0..7
    const int g     = wv >> 1;          // vertical row-group 0..3
    const int half  = wv & 1;           // 0 = cols [0,256), 1 = [256,512)
    const int b     = blockIdx.x;
    const int n     = b >> 5;           // image
    const int vb    = b & 31;           // band within image
    const int hbase = vb << 4;          // band top row
    const int h0    = hbase + (g << 2); // thread's first owned row
    const int w0    = half * 256 + lane * 4;

    // ---- preload owned rows (24 float4, straight-line) ----
    float4 T[3][4], P[3][4];
    #pragma unroll
    for (int c = 0; c < C_CH; ++c) {
        const size_t rb = ((size_t)((n * C_CH + c) * H_DIM + h0)) * W_DIM + w0;
        #pragma unroll
        for (int r = 0; r < 4; ++r) {
            T[c][r] = *(const float4*)(yt + rb + (size_t)r * W_DIM);
            P[c][r] = *(const float4*)(yp + rb + (size_t)r * W_DIM);
        }
    }

    // ---- halo row sums (band-boundary rows; only g==0 / g==3 use) ----
    float rH[5][4];
    #pragma unroll
    for (int s = 0; s < 5; ++s)
        #pragma unroll
        for (int j = 0; j < 4; ++j) rH[s][j] = 0.f;
    if (g == 0 || g == 3) {                      // wave-uniform
        const bool have = (g == 0) ? (vb != 0) : (vb != 31);
        const int  hh   = (g == 0) ? (hbase - 1) : (hbase + 16);
        if (have) {                              // wave-uniform
            #pragma unroll
            for (int c = 0; c < C_CH; ++c) {
                const size_t a = ((size_t)((n * C_CH + c) * H_DIM + hh)) * W_DIM + w0;
                const float4 t = *(const float4*)(yt + a);
                const float4 p = *(const float4*)(yp + a);
                const float tv[4] = {t.x, t.y, t.z, t.w};
                const float pv[4] = {p.x, p.y, p.z, p.w};
                #pragma unroll
                for (int j = 0; j < 4; ++j) {
                    rH[0][j] += tv[j];
                    rH[1][j] += pv[j];
                    rH[2][j] = fmaf(tv[j], tv[j], rH[2][j]);
                    rH[3][j] = fmaf(pv[j], pv[j], rH[3][j]);
                    rH[4][j] = fmaf(tv[j], pv[j], rH[4][j]);
                }
            }
        }
    }

    // ---- per-row column sums for owned rows ----
    float rS[4][5][4];
    #pragma unroll
    for (int r = 0; r < 4; ++r)
        #pragma unroll
        for (int s = 0; s < 5; ++s)
            #pragma unroll
            for (int j = 0; j < 4; ++j) rS[r][s][j] = 0.f;

    #pragma unroll
    for (int c = 0; c < C_CH; ++c) {
        #pragma unroll
        for (int r = 0; r < 4; ++r) {
            const float tv[4] = {T[c][r].x, T[c][r].y, T[c][r].z, T[c][r].w};
            const float pv[4] = {P[c][r].x, P[c][r].y, P[c][r].z, P[c][r].w};
            #pragma unroll
            for (int j = 0; j < 4; ++j) {
                rS[r][0][j] += tv[j];
                rS[r][1][j] += pv[j];
                rS[r][2][j] = fmaf(tv[j], tv[j], rS[r][2][j]);
                rS[r][3][j] = fmaf(pv[j], pv[j], rS[r][3][j]);
                rS[r][4][j] = fmaf(tv[j], pv[j], rS[r][4][j]);
            }
        }
    }

    // ---- vertical rowsum exchange: ONE merged publish phase ----
    // slot 0 (rows 0..19): this thread's bottom rowsum rS[3]
    // slot 1 (rows 20..39): this thread's top rowsum rS[0]
    __shared__ float pub[40][BLOCK];
    #pragma unroll
    for (int s = 0; s < 5; ++s)
        #pragma unroll
        for (int j = 0; j < 4; ++j) {
            pub[s * 4 + j][tid]      = rS[3][s][j];
            pub[20 + s * 4 + j][tid] = rS[0][s][j];
        }
    __syncthreads();

    float rPrev[5][4], rNext[5][4];
    if (g > 0) {
        const int src = ((g - 1) * 2 + half) * 64 + lane;
        #pragma unroll
        for (int s = 0; s < 5; ++s)
            #pragma unroll
            for (int j = 0; j < 4; ++j) rPrev[s][j] = pub[s * 4 + j][src];
    } else {
        #pragma unroll
        for (int s = 0; s < 5; ++s)
            #pragma unroll
            for (int j = 0; j < 4; ++j) rPrev[s][j] = rH[s][j];
    }
    if (g < 3) {
        const int src = ((g + 1) * 2 + half) * 64 + lane;
        #pragma unroll
        for (int s = 0; s < 5; ++s)
            #pragma unroll
            for (int j = 0; j < 4; ++j) rNext[s][j] = pub[20 + s * 4 + j][src];
    } else {
        #pragma unroll
        for (int s = 0; s < 5; ++s)
            #pragma unroll
            for (int j = 0; j < 4; ++j) rNext[s][j] = rH[s][j];
    }

    // ---- vertical 3-row window sums ----
    float wS[4][5][4];
    #pragma unroll
    for (int s = 0; s < 5; ++s)
        #pragma unroll
        for (int j = 0; j < 4; ++j) {
            wS[0][s][j] = rPrev[s][j] + rS[0][s][j] + rS[1][s][j];
            wS[1][s][j] = rS[0][s][j] + rS[1][s][j] + rS[2][s][j];
            wS[2][s][j] = rS[1][s][j] + rS[2][s][j] + rS[3][s][j];
            wS[3][s][j] = rS[2][s][j] + rS[3][s][j] + rNext[s][j];
        }

    // ---- horizontal halo: edge publish + post-hoc shfl ----
    __shared__ float eL[8][4][5];
    __shared__ float eR[8][4][5];
    if (lane == 0) {
        #pragma unroll
        for (int o = 0; o < 4; ++o)
            #pragma unroll
            for (int s = 0; s < 5; ++s) eL[wv][o][s] = wS[o][s][0];
    }
    if (lane == 63) {
        #pragma unroll
        for (int o = 0; o < 4; ++o)
            #pragma unroll
            for (int s = 0; s < 5; ++s) eR[wv][o][s] = wS[o][s][3];
    }
    __syncthreads();

    float lh[4][5], rh[4][5];
    #pragma unroll
    for (int o = 0; o < 4; ++o)
        #pragma unroll
        for (int s = 0; s < 5; ++s) {
            lh[o][s] = __shfl_up(wS[o][s][3], 1);
            rh[o][s] = __shfl_down(wS[o][s][0], 1);
        }
    if (lane == 0) {
        #pragma unroll
        for (int o = 0; o < 4; ++o)
            #pragma unroll
            for (int s = 0; s < 5; ++s)
                lh[o][s] = (half == 1) ? eR[wv - 1][o][s] : 0.f;
    }
    if (lane == 63) {
        #pragma unroll
        for (int o = 0; o < 4; ++o)
            #pragma unroll
            for (int s = 0; s < 5; ++s)
                rh[o][s] = (half == 0) ? eL[wv + 1][o][s] : 0.f;
    }

    // ---- SSIM epilogue (horizontal prefix sums) ----
    const float C1f = 1.0e-4f;
    const float C2f = 9.0e-4f;
    const float inv_n = 1.f / 27.f;
    const float inv_v = 1.f / 26.f;

    float lsum = 0.f;
    #pragma unroll
    for (int o = 0; o < 4; ++o) {
        float hw[5][4];
        #pragma unroll
        for (int s = 0; s < 5; ++s) {
            const float a0 = wS[o][s][0], a1 = wS[o][s][1];
            const float a2 = wS[o][s][2], a3 = wS[o][s][3];
            const float s01 = a0 + a1, s12 = a1 + a2, s23 = a2 + a3;
            hw[s][0] = lh[o][s] + s01;
            hw[s][1] = s01 + a2;
            hw[s][2] = s12 + a3;
            hw[s][3] = s23 + rh[o][s];
        }
        #pragma unroll
        for (int k = 0; k < 4; ++k) {
            const float st  = hw[0][k];
            const float sp  = hw[1][k];
            const float stt = hw[2][k];
            const float spp = hw[3][k];
            const float stp = hw[4][k];

            const float ut = st * inv_n;
            const float up = sp * inv_n;
            const float vart = (stt - st * st * inv_n) * inv_v;
            const float varp = (spp - sp * sp * inv_n) * inv_v;
            const float cov  = stp * inv_n - ut * up;

            const float num = (2.f * ut * up + C1f) * (2.f * cov + C2f);
            const float den = (ut * ut + up * up + C1f) * (vart + varp + C2f);
            lsum = fmaf(-num * __builtin_amdgcn_rcpf(den), 0.5f, lsum + 0.5f);
        }
    }

    // ---- block reduction -> per-block partial ----
    #pragma unroll
    for (int off = 32; off > 0; off >>= 1)
        lsum += __shfl_down(lsum, off, 64);

    __shared__ float smem[BLOCK / 64];
    if (lane == 0) smem[wv] = lsum;
    __syncthreads();
    if (tid == 0) {
        float s = 0.f;
        #pragma unroll
        for (int i = 0; i < BLOCK / 64; ++i) s += smem[i];
        ws[b] = s;
    }

    // ---- grid-wide sync, then block 0 reduces all partials ----
    cg::this_grid().sync();

    if (b == 0) {
        float v = (tid < GRID) ? ws[tid] : 0.f;
        #pragma unroll
        for (int off = 32; off > 0; off >>= 1)
            v += __shfl_down(v, off, 64);
        if (lane == 0) smem[wv] = v;
        __syncthreads();
        if (tid == 0) {
            float tot = 0.f;
            #pragma unroll
            for (int i = 0; i < BLOCK / 64; ++i) tot += smem[i];
            out[0] = tot * (1.f / (float)(N_IMG * H_DIM * W_DIM));
        }
    }
}

extern "C" void kernel_launch(void* const* d_in, const int* in_sizes, int n_in,
                              void* d_out, int out_size, void* d_ws, size_t ws_size,
                              hipStream_t stream) {
    const float* yp = (const float*)d_in[0];   // y_pred
    const float* yt = (const float*)d_in[1];   // y_true
    float* out = (float*)d_out;
    float* ws  = (float*)d_ws;

    void* args[] = {(void*)&yp, (void*)&yt, (void*)&ws, (void*)&out};
    hipLaunchCooperativeKernel((const void*)dssim_coop, dim3(GRID), dim3(BLOCK),
                               args, 0, stream);
}

// Round 10
// 20.372 us; speedup vs baseline: 2.7038x; 2.7038x over previous
//
#include <hip/hip_runtime.h>

// DSSIM loss: y_pred, y_true [8,3,512,512] fp32 -> scalar mean DSSIM.
// R10: wave = 16 lanes (cols) x 4 lanes (row-groups) covering 64 cols x 16
// rows. Thread = 4 cols x 4 rows, each input row loaded once (1.125x bytes).
// Vertical rowsum exchange via __shfl(+-16) -- no LDS pub, no extra syncs
// (was 80KB LDS + 2 syncs in R8). Horizontal halo via __shfl(+-1) + 5KB
// cross-wave edge patch (1 sync). Preload-all-24 straight-line (R7 lesson).
// 2 dispatches: partial -> d_ws, tiny reduce kernel (coop launch regressed).

#define N_IMG 8
#define C_CH 3
#define H_DIM 512
#define W_DIM 512
#define BLOCK 512
#define GRID 256   // 8 img x 32 bands of 16 rows; block = band x 512 cols

__global__ __launch_bounds__(BLOCK, 2) void dssim_partial(
        const float* __restrict__ yp,
        const float* __restrict__ yt,
        float* __restrict__ ws) {
    const int tid  = threadIdx.x;
    const int lane = tid & 63;
    const int wc   = tid >> 6;          // wave = 64-col slab, 0..7
    const int rg   = lane >> 4;         // row-group within wave, 0..3
    const int cl   = lane & 15;         // col-thread within row-group
    const int b    = blockIdx.x;
    const int n    = b >> 5;            // image
    const int vb   = b & 31;            // 16-row band within image
    const int h0   = (vb << 4) + (rg << 2);   // first owned row
    const int w0   = (wc << 6) + (cl << 2);   // first owned col

    // ---- preload owned rows: 24 float4, straight-line ----
    float4 T[3][4], P[3][4];
    #pragma unroll
    for (int c = 0; c < C_CH; ++c) {
        const size_t rb = ((size_t)((n * C_CH + c) * H_DIM + h0)) * W_DIM + w0;
        #pragma unroll
        for (int r = 0; r < 4; ++r) {
            T[c][r] = *(const float4*)(yt + rb + (size_t)r * W_DIM);
            P[c][r] = *(const float4*)(yp + rb + (size_t)r * W_DIM);
        }
    }

    // ---- band-boundary halo rowsums (rg0: row h0-1, rg3: row h0+4) ----
    float rH[5][4];
    #pragma unroll
    for (int s = 0; s < 5; ++s)
        #pragma unroll
        for (int j = 0; j < 4; ++j) rH[s][j] = 0.f;
    {
        const bool need = (rg == 0) ? (vb != 0) : ((rg == 3) ? (vb != 31) : false);
        if (need) {
            const int hh = (rg == 0) ? (h0 - 1) : (h0 + 4);
            #pragma unroll
            for (int c = 0; c < C_CH; ++c) {
                const size_t a = ((size_t)((n * C_CH + c) * H_DIM + hh)) * W_DIM + w0;
                const float4 t = *(const float4*)(yt + a);
                const float4 p = *(const float4*)(yp + a);
                const float tv[4] = {t.x, t.y, t.z, t.w};
                const float pv[4] = {p.x, p.y, p.z, p.w};
                #pragma unroll
                for (int j = 0; j < 4; ++j) {
                    rH[0][j] += tv[j];
                    rH[1][j] += pv[j];
                    rH[2][j] = fmaf(tv[j], tv[j], rH[2][j]);
                    rH[3][j] = fmaf(pv[j], pv[j], rH[3][j]);
                    rH[4][j] = fmaf(tv[j], pv[j], rH[4][j]);
                }
            }
        }
    }

    // ---- per-row column sums ----
    float rS[4][5][4];
    #pragma unroll
    for (int r = 0; r < 4; ++r)
        #pragma unroll
        for (int s = 0; s < 5; ++s)
            #pragma unroll
            for (int j = 0; j < 4; ++j) rS[r][s][j] = 0.f;

    #pragma unroll
    for (int c = 0; c < C_CH; ++c) {
        #pragma unroll
        for (int r = 0; r < 4; ++r) {
            const float tv[4] = {T[c][r].x, T[c][r].y, T[c][r].z, T[c][r].w};
            const float pv[4] = {P[c][r].x, P[c][r].y, P[c][r].z, P[c][r].w};
            #pragma unroll
            for (int j = 0; j < 4; ++j) {
                rS[r][0][j] += tv[j];
                rS[r][1][j] += pv[j];
                rS[r][2][j] = fmaf(tv[j], tv[j], rS[r][2][j]);
                rS[r][3][j] = fmaf(pv[j], pv[j], rS[r][3][j]);
                rS[r][4][j] = fmaf(tv[j], pv[j], rS[r][4][j]);
            }
        }
    }

    // ---- vertical rowsum exchange via intra-wave shfl (no LDS, no sync) ----
    float rPrev[5][4], rNext[5][4];
    #pragma unroll
    for (int s = 0; s < 5; ++s)
        #pragma unroll
        for (int j = 0; j < 4; ++j) {
            const float up = __shfl_up(rS[3][s][j], 16);    // rg-1's bottom row
            const float dn = __shfl_down(rS[0][s][j], 16);  // rg+1's top row
            rPrev[s][j] = (rg == 0) ? rH[s][j] : up;
            rNext[s][j] = (rg == 3) ? rH[s][j] : dn;
        }

    // ---- vertical 3-row window sums ----
    float wS[4][5][4];
    #pragma unroll
    for (int s = 0; s < 5; ++s)
        #pragma unroll
        for (int j = 0; j < 4; ++j) {
            const float r01 = rS[0][s][j] + rS[1][s][j];
            const float r12 = rS[1][s][j] + rS[2][s][j];
            const float r23 = rS[2][s][j] + rS[3][s][j];
            wS[0][s][j] = rPrev[s][j] + r01;
            wS[1][s][j] = r01 + rS[2][s][j];
            wS[2][s][j] = r12 + rS[3][s][j];
            wS[3][s][j] = r23 + rNext[s][j];
        }

    // ---- cross-wave horizontal edge publish ----
    __shared__ float eL[8][4][4][5];   // [wc][rg][o][s]: col w0 window sums of cl==0
    __shared__ float eR[8][4][4][5];   // cl==15's col w0+3 window sums
    if (cl == 0) {
        #pragma unroll
        for (int o = 0; o < 4; ++o)
            #pragma unroll
            for (int s = 0; s < 5; ++s) eL[wc][rg][o][s] = wS[o][s][0];
    }
    if (cl == 15) {
        #pragma unroll
        for (int o = 0; o < 4; ++o)
            #pragma unroll
            for (int s = 0; s < 5; ++s) eR[wc][rg][o][s] = wS[o][s][3];
    }
    __syncthreads();

    // ---- horizontal halo via shfl(+-1) + edge patch ----
    float lh[4][5], rh[4][5];
    #pragma unroll
    for (int o = 0; o < 4; ++o)
        #pragma unroll
        for (int s = 0; s < 5; ++s) {
            lh[o][s] = __shfl_up(wS[o][s][3], 1);
            rh[o][s] = __shfl_down(wS[o][s][0], 1);
        }
    if (cl == 0) {
        #pragma unroll
        for (int o = 0; o < 4; ++o)
            #pragma unroll
            for (int s = 0; s < 5; ++s)
                lh[o][s] = (wc > 0) ? eR[wc - 1][rg][o][s] : 0.f;
    }
    if (cl == 15) {
        #pragma unroll
        for (int o = 0; o < 4; ++o)
            #pragma unroll
            for (int s = 0; s < 5; ++s)
                rh[o][s] = (wc < 7) ? eL[wc + 1][rg][o][s] : 0.f;
    }

    // ---- SSIM epilogue (horizontal prefix sums) ----
    const float C1f = 1.0e-4f;
    const float C2f = 9.0e-4f;
    const float inv_n = 1.f / 27.f;
    const float inv_v = 1.f / 26.f;

    float lsum = 0.f;
    #pragma unroll
    for (int o = 0; o < 4; ++o) {
        float hw[5][4];
        #pragma unroll
        for (int s = 0; s < 5; ++s) {
            const float a0 = wS[o][s][0], a1 = wS[o][s][1];
            const float a2 = wS[o][s][2], a3 = wS[o][s][3];
            const float s01 = a0 + a1, s12 = a1 + a2, s23 = a2 + a3;
            hw[s][0] = lh[o][s] + s01;
            hw[s][1] = s01 + a2;
            hw[s][2] = s12 + a3;
            hw[s][3] = s23 + rh[o][s];
        }
        #pragma unroll
        for (int k = 0; k < 4; ++k) {
            const float st  = hw[0][k];
            const float sp  = hw[1][k];
            const float stt = hw[2][k];
            const float spp = hw[3][k];
            const float stp = hw[4][k];

            const float ut = st * inv_n;
            const float up = sp * inv_n;
            const float vart = (stt - st * st * inv_n) * inv_v;
            const float varp = (spp - sp * sp * inv_n) * inv_v;
            const float cov  = stp * inv_n - ut * up;

            const float num = (2.f * ut * up + C1f) * (2.f * cov + C2f);
            const float den = (ut * ut + up * up + C1f) * (vart + varp + C2f);
            lsum = fmaf(-num * __builtin_amdgcn_rcpf(den), 0.5f, lsum + 0.5f);
        }
    }

    // ---- block reduction -> per-block partial ----
    #pragma unroll
    for (int off = 32; off > 0; off >>= 1)
        lsum += __shfl_down(lsum, off, 64);

    __shared__ float smem[BLOCK / 64];
    if (lane == 0) smem[wc] = lsum;
    __syncthreads();
    if (tid == 0) {
        float s = 0.f;
        #pragma unroll
        for (int i = 0; i < BLOCK / 64; ++i) s += smem[i];
        ws[b] = s;
    }
}

__global__ __launch_bounds__(256) void dssim_reduce(
        const float* __restrict__ ws, float* __restrict__ out) {
    const int t = threadIdx.x;
    float s = ws[t];                    // 256 partials, 256 threads
    #pragma unroll
    for (int off = 32; off > 0; off >>= 1)
        s += __shfl_down(s, off, 64);
    __shared__ float smem[4];
    const int lane = t & 63, wv = t >> 6;
    if (lane == 0) smem[wv] = s;
    __syncthreads();
    if (t == 0) {
        const float tot = smem[0] + smem[1] + smem[2] + smem[3];
        out[0] = tot * (1.f / (float)(N_IMG * H_DIM * W_DIM));
    }
}

extern "C" void kernel_launch(void* const* d_in, const int* in_sizes, int n_in,
                              void* d_out, int out_size, void* d_ws, size_t ws_size,
                              hipStream_t stream) {
    const float* yp = (const float*)d_in[0];   // y_pred
    const float* yt = (const float*)d_in[1];   // y_true
    float* out = (float*)d_out;
    float* ws  = (float*)d_ws;

    dssim_partial<<<GRID, BLOCK, 0, stream>>>(yp, yt, ws);
    dssim_reduce<<<1, 256, 0, stream>>>(ws, out);
}